// Round 1
// baseline (112.507 us; speedup 1.0000x reference)
//
#include <hip/hip_runtime.h>

// Median filter 1D, k=9, replicate padding. x: [B*C rows, L=8192] fp32.
// Tile: 1024 outputs per 256-thread block (4 outputs/thread), LDS-staged with
// 4-element halo on each side.

#define TILE 1024
#define BLOCK 256
#define HALO 4   // (k-1)/2 with k=9

__device__ __forceinline__ void sort3(float a, float b, float c,
                                      float& lo, float& md, float& hi) {
    lo = fminf(fminf(a, b), c);                  // -> v_min3_f32
    hi = fmaxf(fmaxf(a, b), c);                  // -> v_max3_f32
    md = __builtin_amdgcn_fmed3f(a, b, c);       // -> v_med3_f32
}

// Exact median of 9: sort each triple, then med3(max(lows), med(mids), min(highs)).
__device__ __forceinline__ float med9(const float* p) {
    float l0, m0, h0, l1, m1, h1, l2, m2, h2;
    sort3(p[0], p[1], p[2], l0, m0, h0);
    sort3(p[3], p[4], p[5], l1, m1, h1);
    sort3(p[6], p[7], p[8], l2, m2, h2);
    float lo = fmaxf(fmaxf(l0, l1), l2);
    float md = __builtin_amdgcn_fmed3f(m0, m1, m2);
    float hi = fminf(fminf(h0, h1), h2);
    return __builtin_amdgcn_fmed3f(lo, md, hi);
}

__global__ __launch_bounds__(BLOCK) void median9_kernel(
    const float* __restrict__ x, float* __restrict__ out, int L, int tilesPerRow) {
    __shared__ __align__(16) float s[TILE + 2 * HALO];

    const int tid = threadIdx.x;
    const int row = blockIdx.x / tilesPerRow;
    const int tile_start = (blockIdx.x % tilesPerRow) * TILE;
    const long long row_base = (long long)row * L;
    const float* xr = x + row_base;

    // Main coalesced load: 256 threads x float4 = 1024 floats (always in-row:
    // L is a multiple of TILE).
    float4 v = ((const float4*)(xr + tile_start))[tid];
    ((float4*)(s + HALO))[tid] = v;

    // Halo: 8 scalar loads with replicate-pad clamping.
    if (tid < 2 * HALO) {
        int pos, sidx;
        if (tid < HALO) {
            pos = tile_start - HALO + tid;
            sidx = tid;
        } else {
            pos = tile_start + TILE + (tid - HALO);
            sidx = TILE + HALO + (tid - HALO);
        }
        pos = min(max(pos, 0), L - 1);
        s[sidx] = xr[pos];
    }
    __syncthreads();

    // Each thread: 12 contiguous LDS floats -> 4 medians.
    const float4* sv = (const float4*)(s + 4 * tid);   // 16B aligned
    float4 a = sv[0], b = sv[1], c = sv[2];
    float w[12] = {a.x, a.y, a.z, a.w,
                   b.x, b.y, b.z, b.w,
                   c.x, c.y, c.z, c.w};
    float4 r;
    r.x = med9(w + 0);
    r.y = med9(w + 1);
    r.z = med9(w + 2);
    r.w = med9(w + 3);

    ((float4*)(out + row_base + tile_start))[tid] = r;
}

extern "C" void kernel_launch(void* const* d_in, const int* in_sizes, int n_in,
                              void* d_out, int out_size, void* d_ws, size_t ws_size,
                              hipStream_t stream) {
    const float* x = (const float*)d_in[0];
    float* out = (float*)d_out;
    const int L = 8192;                 // static per the reference setup
    const int rows = in_sizes[0] / L;   // 32*64 = 2048
    const int tilesPerRow = L / TILE;   // 8
    const int nblocks = rows * tilesPerRow;
    median9_kernel<<<nblocks, BLOCK, 0, stream>>>(x, out, L, tilesPerRow);
}